// Round 7
// baseline (31576.169 us; speedup 1.0000x reference)
//
#include <hip/hip_runtime.h>
#include <hip/hip_fp16.h>

#define BB 32
#define LL 512
#define HH 1024
#define NL 4
#define RS 8     // h ring slots per layer
#define TPL 32   // blocks (tiles) per layer
#define CPB 32   // output cols per block
#define TAGM 0x0001000100010001ULL   // LSB of each f16 in an 8B quantum

typedef unsigned long long ull;
typedef _Float16 f16x8 __attribute__((ext_vector_type(8)));
typedef float    f32x4 __attribute__((ext_vector_type(4)));

__device__ __forceinline__ f16x8 cvt8(const float* __restrict__ p) {
  f32x4 lo = *reinterpret_cast<const f32x4*>(p);
  f32x4 hi = *reinterpret_cast<const f32x4*>(p + 4);
  f16x8 r;
#pragma unroll
  for (int e = 0; e < 4; ++e) { r[e] = (_Float16)lo[e]; r[e + 4] = (_Float16)hi[e]; }
  return r;
}

// ---- Tier 3 (round-6-proven): MALL atomic spin. Always terminates. ----
__device__ __forceinline__ void spin_load_row16(f16x8* __restrict__ o,
                                                const _Float16* __restrict__ base,
                                                ull wantv) {
  const ull* p = reinterpret_cast<const ull*>(base);
  ull q0[16], q1[16];
#pragma unroll
  for (int j = 0; j < 16; ++j) {
    q0[j] = __hip_atomic_load(p + j * 8,     __ATOMIC_RELAXED, __HIP_MEMORY_SCOPE_AGENT);
    q1[j] = __hip_atomic_load(p + j * 8 + 1, __ATOMIC_RELAXED, __HIP_MEMORY_SCOPE_AGENT);
  }
  for (;;) {
    ull bad = 0;
#pragma unroll
    for (int j = 0; j < 16; ++j)
      bad |= ((q0[j] ^ wantv) | (q1[j] ^ wantv)) & TAGM;
    if (bad == 0) break;
#pragma unroll
    for (int j = 0; j < 16; ++j) {
      q0[j] = __hip_atomic_load(p + j * 8,     __ATOMIC_RELAXED, __HIP_MEMORY_SCOPE_AGENT);
      q1[j] = __hip_atomic_load(p + j * 8 + 1, __ATOMIC_RELAXED, __HIP_MEMORY_SCOPE_AGENT);
    }
  }
#pragma unroll
  for (int j = 0; j < 16; ++j) {
    union { ull u[2]; f16x8 v; } c;
    c.u[0] = q0[j]; c.u[1] = q1[j];
    o[j] = c.v;
  }
}

// ---- Tier 1: one plain cached 16B-vector pass (L1/L2). Fast when producer
// is already done and L1 has evicted the slot (streaming guarantees ~always). ----
__device__ __forceinline__ bool try_plain16(f16x8* __restrict__ o,
                                            const _Float16* __restrict__ base,
                                            ull wantv) {
  f16x8 tmp[16];
#pragma unroll
  for (int j = 0; j < 16; ++j)
    tmp[j] = *reinterpret_cast<const f16x8*>(base + j * 32);
  ull bad = 0;
#pragma unroll
  for (int j = 0; j < 16; ++j) {
    union { f16x8 v; ull u[2]; } c; c.v = tmp[j];
    bad |= ((c.u[0] ^ wantv) | (c.u[1] ^ wantv)) & TAGM;
  }
  if (bad) return false;
#pragma unroll
  for (int j = 0; j < 16; ++j) o[j] = tmp[j];
  return true;
}

// ---- Tier 2: bounded sc0 spin (bypass L1, served by local-XCD L2).
// Succeeds iff producer shares our L2 (mapping heuristic holds). ----
__device__ __forceinline__ bool l2_spin_row16(f16x8* __restrict__ o,
                                              const _Float16* __restrict__ base,
                                              ull wantv) {
  for (int tries = 0; tries < 64; ++tries) {
    ull q[32];
#pragma unroll
    for (int j = 0; j < 16; ++j) {
      asm volatile("global_load_dwordx2 %0, %1, off sc0"
                   : "=v"(q[2 * j]) : "v"(base + j * 32));
      asm volatile("global_load_dwordx2 %0, %1, off sc0"
                   : "=v"(q[2 * j + 1]) : "v"(base + j * 32 + 4));
    }
    asm volatile("s_waitcnt vmcnt(0)" ::: "memory");
    __builtin_amdgcn_sched_barrier(0);   // rule #18: no use hoisted above the wait
    ull bad = 0;
#pragma unroll
    for (int j = 0; j < 32; ++j) bad |= (q[j] ^ wantv) & TAGM;
    if (bad == 0) {
#pragma unroll
      for (int j = 0; j < 16; ++j) {
        union { ull u[2]; f16x8 v; } c;
        c.u[0] = q[2 * j]; c.u[1] = q[2 * j + 1];
        o[j] = c.v;
      }
      return true;
    }
    __builtin_amdgcn_s_sleep(2);
  }
  return false;
}

__device__ __forceinline__ void load_row16(f16x8* __restrict__ o,
                                           const _Float16* __restrict__ fastb,
                                           const _Float16* __restrict__ mallb,
                                           ull wantv) {
  if (try_plain16(o, fastb, wantv)) return;
  if (l2_spin_row16(o, fastb, wantv)) return;
  spin_load_row16(o, mallb, wantv);   // guaranteed-correct, guaranteed-terminating
}

// Persistent pipeline, 128 active blocks: layer = blockIdx&7 (XCD heuristic only;
// every h read is tag-validated with a MALL fallback, so correctness never
// depends on placement). Block: 32 cols, weights in VGPRs; waves 0-1 input
// GEMM, waves 2-3 hidden GEMM. h broadcast served from per-XCD L2 (hA/hC),
// MALL (hB) is master + fallback.
__global__ __launch_bounds__(256, 1) void rnn_persist(
    const float* __restrict__ x,   // [B][L][H] f32
    const float* __restrict__ h0,  // [NL][B][H] f32
    const float* __restrict__ WI,  // [NL][H][H] f32
    const float* __restrict__ BI,  // [NL][H]
    const float* __restrict__ WH,  // [NL][H][H] f32
    const float* __restrict__ BH,  // [NL][H]
    float* __restrict__ out,       // [B][L][H] f32 ++ hfinal [NL][B][H]
    _Float16* __restrict__ hA,     // [NL][RS][B][H] own-layer L2 copy (plain stores)
    _Float16* __restrict__ hB,     // [NL][RS][B][H] MALL master (atomic stores)
    _Float16* __restrict__ hC,     // [NL][RS][B][H] staged copy of h_{l-1} for layer l
    unsigned* __restrict__ pflag) {// [NL][TPL]: t+1 after step t (WAR gating)
  const int l = blockIdx.x & 7;
  if (l >= NL) return;
  const int tile = blockIdx.x >> 3;   // 0..31
  const int c0   = tile * CPB;
  const int tid  = threadIdx.x;
  const int w    = tid >> 6;          // wave 0..3
  const int lane = tid & 63;
  const int crow = lane & 15;
  const int kgrp = lane >> 4;
  const int kofs = (w & 1) * 512;     // k offset within the 1024-wide matrix

  // ---- weight fragments -> registers (once) ----
  f16x8 wfrag[2][16];
  {
    const float* Wb = (w < 2 ? WI : WH) + (size_t)l * HH * HH;
#pragma unroll
    for (int ct = 0; ct < 2; ++ct) {
      const float* wr = Wb + (size_t)(c0 + ct * 16 + crow) * HH + kofs + kgrp * 8;
#pragma unroll
      for (int j = 0; j < 16; ++j) wfrag[ct][j] = cvt8(wr + j * 32);
    }
  }

  // ---- epilogue assignment: thread -> (batch row rb, 4 cols at c4) ----
  const int rb = tid >> 3;          // 0..31
  const int c4 = (tid & 7) * 4;     // 0,4,...,28
  float bias[4];
#pragma unroll
  for (int j = 0; j < 4; ++j)
    bias[j] = BI[l * HH + c0 + c4 + j] + BH[l * HH + c0 + c4 + j];

  __shared__ float red[2][4][2][16][34];   // [pingpong][wave][rowtile][row][col+pad]

  for (int t = 0; t < LL; ++t) {
    const ull wantI = ((t >> 3) & 1) ? TAGM : 0ULL;          // gen t
    const ull wantH = (((t - 1) >> 3) & 1) ? TAGM : 0ULL;    // gen t-1 (t>=1)

    // ---------- WAR gate (round-6 conditions, verbatim) ----------
    if (t >= RS && tid < 64) {
      const int Lt = tid & 31;
      if (tid < 32) {        // own-layer peers past step t-7 (consumed gen t-8)
        while (__hip_atomic_load(&pflag[l * TPL + Lt], __ATOMIC_RELAXED,
                                 __HIP_MEMORY_SCOPE_AGENT) < (unsigned)(t - 6))
          __builtin_amdgcn_s_sleep(1);
      } else if (l < NL - 1) {  // layer l+1 past step t-8 (staged+consumed gen t-8)
        while (__hip_atomic_load(&pflag[(l + 1) * TPL + Lt], __ATOMIC_RELAXED,
                                 __HIP_MEMORY_SCOPE_AGENT) < (unsigned)(t - 7))
          __builtin_amdgcn_s_sleep(1);
      }
    }
    __syncthreads();   // all lanes' WAR polls done before any store below

    // ---------- cooperative staging: this block copies its 1/32 of h_{l-1}
    // gen t from hB (MALL) into hC (lands in this XCD's L2). 1 quantum/thread.
    if (l > 0) {
      const int q = tile * 256 + tid;   // [0, 8192)
      const ull* src = reinterpret_cast<const ull*>(
          hB + ((size_t)((l - 1) * RS + (t & (RS - 1))) * BB) * HH) + q;
      ull v;
      while ((((v = __hip_atomic_load(src, __ATOMIC_RELAXED,
                                      __HIP_MEMORY_SCOPE_AGENT)) ^ wantI) & TAGM) != 0)
        __builtin_amdgcn_s_sleep(2);
      reinterpret_cast<ull*>(
          hC + ((size_t)(l * RS + (t & (RS - 1))) * BB) * HH)[q] = v;
    }

    // ---------- phased operand load + MFMA ----------
    f32x4 acc[2][2];
#pragma unroll
    for (int ct = 0; ct < 2; ++ct)
#pragma unroll
      for (int rt = 0; rt < 2; ++rt) acc[ct][rt] = (f32x4){0.f, 0.f, 0.f, 0.f};

#pragma unroll
    for (int rt = 0; rt < 2; ++rt) {
      f16x8 af[16];
      const size_t rowoff = (size_t)(rt * 16 + crow) * HH + kofs + kgrp * 8;
      if (w < 2) {            // input operand: x (l==0) or h_{l-1} gen t
        if (l == 0) {
          const float* r = x + ((size_t)(rt * 16 + crow) * LL + t) * HH + kofs + kgrp * 8;
#pragma unroll
          for (int j = 0; j < 16; ++j) af[j] = cvt8(r + j * 32);
        } else {
          const size_t slotC = (size_t)(l * RS + (t & (RS - 1))) * BB * HH;
          const size_t slotB = (size_t)((l - 1) * RS + (t & (RS - 1))) * BB * HH;
          load_row16(af, hC + slotC + rowoff, hB + slotB + rowoff, wantI);
        }
      } else {                // hidden operand: h0 (t==0) or own h gen t-1
        if (t == 0) {
          const float* r = h0 + ((size_t)l * BB + rt * 16 + crow) * HH + kofs + kgrp * 8;
#pragma unroll
          for (int j = 0; j < 16; ++j) af[j] = cvt8(r + j * 32);
        } else {
          const size_t slot = (size_t)(l * RS + ((t - 1) & (RS - 1))) * BB * HH;
          load_row16(af, hA + slot + rowoff, hB + slot + rowoff, wantH);
        }
      }
#pragma unroll
      for (int j = 0; j < 16; ++j)
#pragma unroll
        for (int ct = 0; ct < 2; ++ct)
          acc[ct][rt] = __builtin_amdgcn_mfma_f32_16x16x32_f16(af[j], wfrag[ct][j],
                                                               acc[ct][rt], 0, 0, 0);
    }

    // ---------- cross-wave k-reduce via LDS (ping-pong, one barrier) ----------
    const int pp = t & 1;
#pragma unroll
    for (int ct = 0; ct < 2; ++ct)
#pragma unroll
      for (int rt = 0; rt < 2; ++rt)
#pragma unroll
        for (int r = 0; r < 4; ++r)
          red[pp][w][rt][kgrp * 4 + r][ct * 16 + crow] = acc[ct][rt][r];
    __syncthreads();

    float v[4];
#pragma unroll
    for (int j = 0; j < 4; ++j) {
      float s = bias[j];
#pragma unroll
      for (int w2 = 0; w2 < 4; ++w2) s += red[pp][w2][rb >> 4][rb & 15][c4 + j];
      v[j] = tanhf(s);
    }

    // ---------- h stores: tagged 8B quantum to hA (L2) + hB (MALL) ----------
    {
      union { _Float16 h[4]; ull u; } pk;
#pragma unroll
      for (int j = 0; j < 4; ++j) pk.h[j] = (_Float16)v[j];
      pk.u = (pk.u & ~TAGM) | (((t >> 3) & 1) ? TAGM : 0ULL);
      const size_t off = ((size_t)(l * RS + (t & (RS - 1))) * BB + rb) * HH + c0 + c4;
      *reinterpret_cast<ull*>(hA + off) = pk.u;                       // L2-local
      __hip_atomic_store(reinterpret_cast<ull*>(hB + off), pk.u,
                         __ATOMIC_RELAXED, __HIP_MEMORY_SCOPE_AGENT); // MALL master
    }

    // ---------- WAR progress flag (all this block's reads for step t done) ----------
    if (tid == 0)
      __hip_atomic_store(&pflag[l * TPL + tile], (unsigned)(t + 1), __ATOMIC_RELAXED,
                         __HIP_MEMORY_SCOPE_AGENT);

    // ---------- out stores (fire-and-forget) ----------
    if (l == NL - 1) {
      f32x4 o = {v[0], v[1], v[2], v[3]};
      __builtin_nontemporal_store(
          o, reinterpret_cast<f32x4*>(out + ((size_t)rb * LL + t) * HH + c0 + c4));
    }
    if (t == LL - 1) {
      f32x4 o = {v[0], v[1], v[2], v[3]};
      __builtin_nontemporal_store(
          o, reinterpret_cast<f32x4*>(out + (size_t)BB * LL * HH +
                                      ((size_t)l * BB + rb) * HH + c0 + c4));
    }
  }
}

extern "C" void kernel_launch(void* const* d_in, const int* in_sizes, int n_in,
                              void* d_out, int out_size, void* d_ws, size_t ws_size,
                              hipStream_t stream) {
  const float* x  = (const float*)d_in[0];
  const float* h0 = (const float*)d_in[1];
  const float* WI = (const float*)d_in[2];
  const float* BI = (const float*)d_in[3];
  const float* WH = (const float*)d_in[4];
  const float* BH = (const float*)d_in[5];
  float* out = (float*)d_out;

  const size_t hbytes = (size_t)NL * RS * BB * HH * sizeof(_Float16);  // 2 MB
  _Float16* hA = (_Float16*)d_ws;
  _Float16* hB = (_Float16*)((char*)d_ws + hbytes);
  _Float16* hC = (_Float16*)((char*)d_ws + 2 * hbytes);
  unsigned* pflag = (unsigned*)((char*)d_ws + 3 * hbytes);

  // 0xFF: every f16 LSB=1 -> invalid for generation-0 (parity 0) consumers.
  hipMemsetAsync(hA, 0xFF, 3 * hbytes, stream);
  hipMemsetAsync(pflag, 0, (size_t)NL * TPL * sizeof(unsigned), stream);
  rnn_persist<<<256, 256, 0, stream>>>(x, h0, WI, BI, WH, BH, out, hA, hB, hC, pflag);
}

// Round 8
// 7435.461 us; speedup vs baseline: 4.2467x; 4.2467x over previous
//
#include <hip/hip_runtime.h>
#include <hip/hip_fp16.h>

#define BB 32
#define LL 512
#define HH 1024
#define NL 4
#define RS 8     // h ring slots per layer
#define TPL 32   // blocks (tiles) per layer
#define CPB 32   // output cols per block
#define TAGM 0x0001000100010001ULL   // LSB of each f16 in an 8B quantum

typedef unsigned long long ull;
typedef _Float16 f16x8 __attribute__((ext_vector_type(8)));
typedef float    f32x4 __attribute__((ext_vector_type(4)));

__device__ __forceinline__ f16x8 cvt8(const float* __restrict__ p) {
  f32x4 lo = *reinterpret_cast<const f32x4*>(p);
  f32x4 hi = *reinterpret_cast<const f32x4*>(p + 4);
  f16x8 r;
#pragma unroll
  for (int e = 0; e < 4; ++e) { r[e] = (_Float16)lo[e]; r[e + 4] = (_Float16)hi[e]; }
  return r;
}

// Tier A: plain cacheable vector loads (L1+L2 path -> line-dedup'd across the
// XCD's blocks). Valid iff every f16 LSB matches the generation parity.
__device__ __forceinline__ bool try_plain_row16(f16x8* __restrict__ o,
                                                const _Float16* __restrict__ base,
                                                ull wantv) {
  f16x8 tmp[16];
#pragma unroll
  for (int j = 0; j < 16; ++j)
    tmp[j] = *reinterpret_cast<const f16x8*>(base + j * 32);
  ull bad = 0;
#pragma unroll
  for (int j = 0; j < 16; ++j) {
    union { f16x8 v; ull u[2]; } c; c.v = tmp[j];
    bad |= ((c.u[0] ^ wantv) | (c.u[1] ^ wantv)) & TAGM;
  }
  if (bad) return false;
#pragma unroll
  for (int j = 0; j < 16; ++j) o[j] = tmp[j];
  return true;
}

// Tier B (round-6-proven safety net): MALL atomic spin. Always correct,
// always terminates (producer's tagged quanta are at the coherence point).
__device__ __forceinline__ void spin_load_row16(f16x8* __restrict__ o,
                                                const _Float16* __restrict__ base,
                                                ull wantv) {
  const ull* p = reinterpret_cast<const ull*>(base);
  ull q0[16], q1[16];
#pragma unroll
  for (int j = 0; j < 16; ++j) {
    q0[j] = __hip_atomic_load(p + j * 8,     __ATOMIC_RELAXED, __HIP_MEMORY_SCOPE_AGENT);
    q1[j] = __hip_atomic_load(p + j * 8 + 1, __ATOMIC_RELAXED, __HIP_MEMORY_SCOPE_AGENT);
  }
  for (;;) {
    ull bad = 0;
#pragma unroll
    for (int j = 0; j < 16; ++j)
      bad |= ((q0[j] ^ wantv) | (q1[j] ^ wantv)) & TAGM;
    if (bad == 0) break;
#pragma unroll
    for (int j = 0; j < 16; ++j) {
      q0[j] = __hip_atomic_load(p + j * 8,     __ATOMIC_RELAXED, __HIP_MEMORY_SCOPE_AGENT);
      q1[j] = __hip_atomic_load(p + j * 8 + 1, __ATOMIC_RELAXED, __HIP_MEMORY_SCOPE_AGENT);
    }
  }
#pragma unroll
  for (int j = 0; j < 16; ++j) {
    union { ull u[2]; f16x8 v; } c;
    c.u[0] = q0[j]; c.u[1] = q1[j];
    o[j] = c.v;
  }
}

__device__ __forceinline__ void load_row16(f16x8* __restrict__ o,
                                           const _Float16* __restrict__ base,
                                           ull wantv) {
  if (try_plain_row16(o, base, wantv)) return;   // expected path (flag-gated)
  spin_load_row16(o, base, wantv);               // stale-line safety net
}

// Persistent pipeline, 128 active blocks: layer = blockIdx&7 (XCD-locality
// heuristic only; tags+fallback make correctness placement-independent).
// Block: 32 cols, weights in VGPRs; waves 0-1 input GEMM, waves 2-3 hidden.
// Consumption is flag-gated so cacheable h reads are fresh-on-miss and
// line-dedup'd in each XCD's L2 (the round-3..6 floor was 32x redundant
// copies through the per-XCD fabric port).
__global__ __launch_bounds__(256, 1) void rnn_persist(
    const float* __restrict__ x,   // [B][L][H] f32
    const float* __restrict__ h0,  // [NL][B][H] f32
    const float* __restrict__ WI,  // [NL][H][H] f32
    const float* __restrict__ BI,  // [NL][H]
    const float* __restrict__ WH,  // [NL][H][H] f32
    const float* __restrict__ BH,  // [NL][H]
    float* __restrict__ out,       // [B][L][H] f32 ++ hfinal [NL][B][H]
    _Float16* __restrict__ hbuf,   // [NL][RS][B][H] f16 ring (tagged)
    unsigned* __restrict__ pflag) {// [NL][TPL]: t+1 after step t
  const int l = blockIdx.x & 7;
  if (l >= NL) return;
  const int tile = blockIdx.x >> 3;   // 0..31
  const int c0   = tile * CPB;
  const int tid  = threadIdx.x;
  const int w    = tid >> 6;          // wave 0..3
  const int lane = tid & 63;
  const int crow = lane & 15;
  const int kgrp = lane >> 4;
  const int kofs = (w & 1) * 512;     // k offset within the 1024-wide matrix

  // ---- weight fragments -> registers (once) ----
  f16x8 wfrag[2][16];
  {
    const float* Wb = (w < 2 ? WI : WH) + (size_t)l * HH * HH;
#pragma unroll
    for (int ct = 0; ct < 2; ++ct) {
      const float* wr = Wb + (size_t)(c0 + ct * 16 + crow) * HH + kofs + kgrp * 8;
#pragma unroll
      for (int j = 0; j < 16; ++j) wfrag[ct][j] = cvt8(wr + j * 32);
    }
  }

  // ---- epilogue assignment: thread -> (batch row rb, 4 cols at c4) ----
  const int rb = tid >> 3;          // 0..31
  const int c4 = (tid & 7) * 4;     // 0,4,...,28
  float bias[4];
#pragma unroll
  for (int j = 0; j < 4; ++j)
    bias[j] = BI[l * HH + c0 + c4 + j] + BH[l * HH + c0 + c4 + j];

  __shared__ float red[2][4][2][16][34];   // [pingpong][wave][rowtile][row][col+pad]

  for (int t = 0; t < LL; ++t) {
    const ull wantI = ((t >> 3) & 1) ? TAGM : 0ULL;          // gen t (input operand)
    const ull wantH = (((t - 1) >> 3) & 1) ? TAGM : 0ULL;    // gen t-1 (hidden operand)

    // ---------- flag gates: 3 groups x 32 lanes poll in parallel ----------
    // g0: own layer done step t-1  (RAW for h^{t-1}; subsumes own-WAR >= t-6)
    // g1: layer l-1 done step t    (RAW for input h)
    // g2: layer l+1 done step t-8  (WAR: ring slot t&7 free to overwrite)
    if (tid < 96) {
      const int g  = tid >> 5;
      const int Lt = tid & 31;
      if (g == 0) {
        if (t > 0)
          while (__hip_atomic_load(&pflag[l * TPL + Lt], __ATOMIC_RELAXED,
                                   __HIP_MEMORY_SCOPE_AGENT) < (unsigned)t)
            __builtin_amdgcn_s_sleep(1);
      } else if (g == 1) {
        if (l > 0)
          while (__hip_atomic_load(&pflag[(l - 1) * TPL + Lt], __ATOMIC_RELAXED,
                                   __HIP_MEMORY_SCOPE_AGENT) < (unsigned)(t + 1))
            __builtin_amdgcn_s_sleep(1);
      } else {
        if (l < NL - 1 && t >= RS)
          while (__hip_atomic_load(&pflag[(l + 1) * TPL + Lt], __ATOMIC_RELAXED,
                                   __HIP_MEMORY_SCOPE_AGENT) < (unsigned)(t - (RS - 1)))
            __builtin_amdgcn_s_sleep(1);
      }
    }
    __syncthreads();   // all deps satisfied for every wave beyond this point

    // ---------- phased operand load + MFMA ----------
    f32x4 acc[2][2];
#pragma unroll
    for (int ct = 0; ct < 2; ++ct)
#pragma unroll
      for (int rt = 0; rt < 2; ++rt) acc[ct][rt] = (f32x4){0.f, 0.f, 0.f, 0.f};

#pragma unroll
    for (int rt = 0; rt < 2; ++rt) {
      f16x8 af[16];
      const size_t rowoff = (size_t)(rt * 16 + crow) * HH + kofs + kgrp * 8;
      if (w < 2) {            // input operand: x (l==0) or h_{l-1} gen t
        if (l == 0) {
          const float* r = x + ((size_t)(rt * 16 + crow) * LL + t) * HH + kofs + kgrp * 8;
#pragma unroll
          for (int j = 0; j < 16; ++j) af[j] = cvt8(r + j * 32);
        } else {
          const size_t slot = (size_t)((l - 1) * RS + (t & (RS - 1))) * BB * HH;
          load_row16(af, hbuf + slot + rowoff, wantI);
        }
      } else {                // hidden operand: h0 (t==0) or own h gen t-1
        if (t == 0) {
          const float* r = h0 + ((size_t)l * BB + rt * 16 + crow) * HH + kofs + kgrp * 8;
#pragma unroll
          for (int j = 0; j < 16; ++j) af[j] = cvt8(r + j * 32);
        } else {
          const size_t slot = (size_t)(l * RS + ((t - 1) & (RS - 1))) * BB * HH;
          load_row16(af, hbuf + slot + rowoff, wantH);
        }
      }
#pragma unroll
      for (int j = 0; j < 16; ++j)
#pragma unroll
        for (int ct = 0; ct < 2; ++ct)
          acc[ct][rt] = __builtin_amdgcn_mfma_f32_16x16x32_f16(af[j], wfrag[ct][j],
                                                               acc[ct][rt], 0, 0, 0);
    }

    // ---------- cross-wave k-reduce via LDS (ping-pong) ----------
    const int pp = t & 1;
#pragma unroll
    for (int ct = 0; ct < 2; ++ct)
#pragma unroll
      for (int rt = 0; rt < 2; ++rt)
#pragma unroll
        for (int r = 0; r < 4; ++r)
          red[pp][w][rt][kgrp * 4 + r][ct * 16 + crow] = acc[ct][rt][r];
    __syncthreads();

    float v[4];
#pragma unroll
    for (int j = 0; j < 4; ++j) {
      float s = bias[j];
#pragma unroll
      for (int w2 = 0; w2 < 4; ++w2) s += red[pp][w2][rb >> 4][rb & 15][c4 + j];
      v[j] = tanhf(s);
    }

    // ---------- h store: tagged 8B quantum, MALL-visible (round-6-proven) ----------
    {
      union { _Float16 h[4]; ull u; } pk;
#pragma unroll
      for (int j = 0; j < 4; ++j) pk.h[j] = (_Float16)v[j];
      pk.u = (pk.u & ~TAGM) | (((t >> 3) & 1) ? TAGM : 0ULL);
      __hip_atomic_store(
          reinterpret_cast<ull*>(
              hbuf + ((size_t)(l * RS + (t & (RS - 1))) * BB + rb) * HH + c0 + c4),
          pk.u, __ATOMIC_RELAXED, __HIP_MEMORY_SCOPE_AGENT);
    }
    // Drain: every wave waits vmcnt(0) entering the barrier -> all h quanta of
    // this block are at the coherence point before the flag is published.
    __syncthreads();

    // ---------- publish progress ----------
    if (tid == 0)
      __hip_atomic_store(&pflag[l * TPL + tile], (unsigned)(t + 1), __ATOMIC_RELAXED,
                         __HIP_MEMORY_SCOPE_AGENT);

    // ---------- out stores (fire-and-forget, off critical path) ----------
    if (l == NL - 1) {
      f32x4 o = {v[0], v[1], v[2], v[3]};
      __builtin_nontemporal_store(
          o, reinterpret_cast<f32x4*>(out + ((size_t)rb * LL + t) * HH + c0 + c4));
    }
    if (t == LL - 1) {
      f32x4 o = {v[0], v[1], v[2], v[3]};
      __builtin_nontemporal_store(
          o, reinterpret_cast<f32x4*>(out + (size_t)BB * LL * HH +
                                      ((size_t)l * BB + rb) * HH + c0 + c4));
    }
  }
}

extern "C" void kernel_launch(void* const* d_in, const int* in_sizes, int n_in,
                              void* d_out, int out_size, void* d_ws, size_t ws_size,
                              hipStream_t stream) {
  const float* x  = (const float*)d_in[0];
  const float* h0 = (const float*)d_in[1];
  const float* WI = (const float*)d_in[2];
  const float* BI = (const float*)d_in[3];
  const float* WH = (const float*)d_in[4];
  const float* BH = (const float*)d_in[5];
  float* out = (float*)d_out;

  const size_t hbytes = (size_t)NL * RS * BB * HH * sizeof(_Float16);  // 2 MB
  _Float16* hbuf = (_Float16*)d_ws;
  unsigned* pflag = (unsigned*)((char*)d_ws + hbytes);

  // 0xFF: every f16 LSB=1 -> invalid for generation-0 (parity 0) consumers.
  hipMemsetAsync(hbuf, 0xFF, hbytes, stream);
  hipMemsetAsync(pflag, 0, (size_t)NL * TPL * sizeof(unsigned), stream);
  rnn_persist<<<256, 256, 0, stream>>>(x, h0, WI, BI, WH, BH, out, hbuf, pflag);
}

// Round 9
// 7380.638 us; speedup vs baseline: 4.2782x; 1.0074x over previous
//
#include <hip/hip_runtime.h>
#include <hip/hip_fp16.h>

#define BB 32
#define LL 512
#define HH 1024
#define NL 4
#define RS 64    // h ring slots per layer: reuse period must exceed L2 retention
#define RSHIFT 6 // log2(RS) for generation parity
#define TPL 32   // blocks (tiles) per layer
#define CPB 32   // output cols per block
#define TAGM 0x0001000100010001ULL   // LSB of each f16 in an 8B quantum

typedef unsigned long long ull;
typedef _Float16 f16x8 __attribute__((ext_vector_type(8)));
typedef float    f32x4 __attribute__((ext_vector_type(4)));

__device__ __forceinline__ f16x8 cvt8(const float* __restrict__ p) {
  f32x4 lo = *reinterpret_cast<const f32x4*>(p);
  f32x4 hi = *reinterpret_cast<const f32x4*>(p + 4);
  f16x8 r;
#pragma unroll
  for (int e = 0; e < 4; ++e) { r[e] = (_Float16)lo[e]; r[e + 4] = (_Float16)hi[e]; }
  return r;
}

// Tier A: plain cacheable vector loads. With RS=64 the slot's previous-gen
// lines are LRU-evicted before reuse, so this misses -> fetches fresh MALL
// data ONCE per line per XCD and serves the other ~31 blocks from L2 (dedup).
__device__ __forceinline__ bool try_plain_row16(f16x8* __restrict__ o,
                                                const _Float16* __restrict__ base,
                                                ull wantv) {
  f16x8 tmp[16];
#pragma unroll
  for (int j = 0; j < 16; ++j)
    tmp[j] = *reinterpret_cast<const f16x8*>(base + j * 32);
  ull bad = 0;
#pragma unroll
  for (int j = 0; j < 16; ++j) {
    union { f16x8 v; ull u[2]; } c; c.v = tmp[j];
    bad |= ((c.u[0] ^ wantv) | (c.u[1] ^ wantv)) & TAGM;
  }
  if (bad) return false;
#pragma unroll
  for (int j = 0; j < 16; ++j) o[j] = tmp[j];
  return true;
}

// Tier B (round-6-proven safety net): MALL atomic spin. Always correct,
// always terminates (producer's tagged quanta are at the coherence point).
__device__ __forceinline__ void spin_load_row16(f16x8* __restrict__ o,
                                                const _Float16* __restrict__ base,
                                                ull wantv) {
  const ull* p = reinterpret_cast<const ull*>(base);
  ull q0[16], q1[16];
#pragma unroll
  for (int j = 0; j < 16; ++j) {
    q0[j] = __hip_atomic_load(p + j * 8,     __ATOMIC_RELAXED, __HIP_MEMORY_SCOPE_AGENT);
    q1[j] = __hip_atomic_load(p + j * 8 + 1, __ATOMIC_RELAXED, __HIP_MEMORY_SCOPE_AGENT);
  }
  for (;;) {
    ull bad = 0;
#pragma unroll
    for (int j = 0; j < 16; ++j)
      bad |= ((q0[j] ^ wantv) | (q1[j] ^ wantv)) & TAGM;
    if (bad == 0) break;
#pragma unroll
    for (int j = 0; j < 16; ++j) {
      q0[j] = __hip_atomic_load(p + j * 8,     __ATOMIC_RELAXED, __HIP_MEMORY_SCOPE_AGENT);
      q1[j] = __hip_atomic_load(p + j * 8 + 1, __ATOMIC_RELAXED, __HIP_MEMORY_SCOPE_AGENT);
    }
  }
#pragma unroll
  for (int j = 0; j < 16; ++j) {
    union { ull u[2]; f16x8 v; } c;
    c.u[0] = q0[j]; c.u[1] = q1[j];
    o[j] = c.v;
  }
}

__device__ __forceinline__ void load_row16(f16x8* __restrict__ o,
                                           const _Float16* __restrict__ base,
                                           ull wantv) {
  if (try_plain_row16(o, base, wantv)) return;   // expected path (flag-gated)
  spin_load_row16(o, base, wantv);               // stale-line safety net
}

// Persistent pipeline, 128 active blocks: layer = blockIdx&7 (XCD-locality
// heuristic only; tags+fallback make correctness placement-independent).
// Block: 32 cols, weights in VGPRs; waves 0-1 input GEMM, waves 2-3 hidden.
__global__ __launch_bounds__(256, 1) void rnn_persist(
    const float* __restrict__ x,   // [B][L][H] f32
    const float* __restrict__ h0,  // [NL][B][H] f32
    const float* __restrict__ WI,  // [NL][H][H] f32
    const float* __restrict__ BI,  // [NL][H]
    const float* __restrict__ WH,  // [NL][H][H] f32
    const float* __restrict__ BH,  // [NL][H]
    float* __restrict__ out,       // [B][L][H] f32 ++ hfinal [NL][B][H]
    _Float16* __restrict__ hbuf,   // [NL][RS][B][H] f16 ring (tagged)
    unsigned* __restrict__ pflag) {// [NL][TPL]: t+1 after step t
  const int l = blockIdx.x & 7;
  if (l >= NL) return;
  const int tile = blockIdx.x >> 3;   // 0..31
  const int c0   = tile * CPB;
  const int tid  = threadIdx.x;
  const int w    = tid >> 6;          // wave 0..3
  const int lane = tid & 63;
  const int crow = lane & 15;
  const int kgrp = lane >> 4;
  const int kofs = (w & 1) * 512;     // k offset within the 1024-wide matrix

  // ---- weight fragments -> registers (once) ----
  f16x8 wfrag[2][16];
  {
    const float* Wb = (w < 2 ? WI : WH) + (size_t)l * HH * HH;
#pragma unroll
    for (int ct = 0; ct < 2; ++ct) {
      const float* wr = Wb + (size_t)(c0 + ct * 16 + crow) * HH + kofs + kgrp * 8;
#pragma unroll
      for (int j = 0; j < 16; ++j) wfrag[ct][j] = cvt8(wr + j * 32);
    }
  }

  // ---- epilogue assignment: thread -> (batch row rb, 4 cols at c4) ----
  const int rb = tid >> 3;          // 0..31
  const int c4 = (tid & 7) * 4;     // 0,4,...,28
  float bias[4];
#pragma unroll
  for (int j = 0; j < 4; ++j)
    bias[j] = BI[l * HH + c0 + c4 + j] + BH[l * HH + c0 + c4 + j];

  __shared__ float red[2][4][2][16][34];   // [pingpong][wave][rowtile][row][col+pad]

  for (int t = 0; t < LL; ++t) {
    const ull wantI = ((t >> RSHIFT) & 1) ? TAGM : 0ULL;        // gen t (input)
    const ull wantH = (((t - 1) >> RSHIFT) & 1) ? TAGM : 0ULL;  // gen t-1 (hidden)

    // ---------- flag gates: 3 groups x 32 lanes poll in parallel ----------
    // g0: own layer done step t-1 (RAW hidden; also own-peer WAR for slot t&63)
    // g1: layer l-1 done step t   (RAW input h; ensures tier-A caches fresh)
    // g2: layer l+1 done step t-64+1 (WAR: ring slot t&63 free to overwrite)
    if (tid < 96) {
      const int g  = tid >> 5;
      const int Lt = tid & 31;
      if (g == 0) {
        if (t > 0)
          while (__hip_atomic_load(&pflag[l * TPL + Lt], __ATOMIC_RELAXED,
                                   __HIP_MEMORY_SCOPE_AGENT) < (unsigned)t)
            __builtin_amdgcn_s_sleep(1);
      } else if (g == 1) {
        if (l > 0)
          while (__hip_atomic_load(&pflag[(l - 1) * TPL + Lt], __ATOMIC_RELAXED,
                                   __HIP_MEMORY_SCOPE_AGENT) < (unsigned)(t + 1))
            __builtin_amdgcn_s_sleep(1);
      } else {
        if (l < NL - 1 && t >= RS)
          while (__hip_atomic_load(&pflag[(l + 1) * TPL + Lt], __ATOMIC_RELAXED,
                                   __HIP_MEMORY_SCOPE_AGENT) < (unsigned)(t - (RS - 1)))
            __builtin_amdgcn_s_sleep(1);
      }
    }
    __syncthreads();   // all deps satisfied for every wave beyond this point

    // ---------- phased operand load + MFMA ----------
    f32x4 acc[2][2];
#pragma unroll
    for (int ct = 0; ct < 2; ++ct)
#pragma unroll
      for (int rt = 0; rt < 2; ++rt) acc[ct][rt] = (f32x4){0.f, 0.f, 0.f, 0.f};

#pragma unroll
    for (int rt = 0; rt < 2; ++rt) {
      f16x8 af[16];
      const size_t rowoff = (size_t)(rt * 16 + crow) * HH + kofs + kgrp * 8;
      if (w < 2) {            // input operand: x (l==0) or h_{l-1} gen t
        if (l == 0) {
          const float* r = x + ((size_t)(rt * 16 + crow) * LL + t) * HH + kofs + kgrp * 8;
#pragma unroll
          for (int j = 0; j < 16; ++j) af[j] = cvt8(r + j * 32);
        } else {
          const size_t slot = (size_t)((l - 1) * RS + (t & (RS - 1))) * BB * HH;
          load_row16(af, hbuf + slot + rowoff, wantI);
        }
      } else {                // hidden operand: h0 (t==0) or own h gen t-1
        if (t == 0) {
          const float* r = h0 + ((size_t)l * BB + rt * 16 + crow) * HH + kofs + kgrp * 8;
#pragma unroll
          for (int j = 0; j < 16; ++j) af[j] = cvt8(r + j * 32);
        } else {
          const size_t slot = (size_t)(l * RS + ((t - 1) & (RS - 1))) * BB * HH;
          load_row16(af, hbuf + slot + rowoff, wantH);
        }
      }
#pragma unroll
      for (int j = 0; j < 16; ++j)
#pragma unroll
        for (int ct = 0; ct < 2; ++ct)
          acc[ct][rt] = __builtin_amdgcn_mfma_f32_16x16x32_f16(af[j], wfrag[ct][j],
                                                               acc[ct][rt], 0, 0, 0);
    }

    // ---------- cross-wave k-reduce via LDS (ping-pong) ----------
    const int pp = t & 1;
#pragma unroll
    for (int ct = 0; ct < 2; ++ct)
#pragma unroll
      for (int rt = 0; rt < 2; ++rt)
#pragma unroll
        for (int r = 0; r < 4; ++r)
          red[pp][w][rt][kgrp * 4 + r][ct * 16 + crow] = acc[ct][rt][r];
    __syncthreads();

    float v[4];
#pragma unroll
    for (int j = 0; j < 4; ++j) {
      float s = bias[j];
#pragma unroll
      for (int w2 = 0; w2 < 4; ++w2) s += red[pp][w2][rb >> 4][rb & 15][c4 + j];
      v[j] = tanhf(s);
    }

    // ---------- h store: tagged 8B quantum, MALL-visible (round-6-proven) ----------
    {
      union { _Float16 h[4]; ull u; } pk;
#pragma unroll
      for (int j = 0; j < 4; ++j) pk.h[j] = (_Float16)v[j];
      pk.u = (pk.u & ~TAGM) | (((t >> RSHIFT) & 1) ? TAGM : 0ULL);
      __hip_atomic_store(
          reinterpret_cast<ull*>(
              hbuf + ((size_t)(l * RS + (t & (RS - 1))) * BB + rb) * HH + c0 + c4),
          pk.u, __ATOMIC_RELAXED, __HIP_MEMORY_SCOPE_AGENT);
    }
    // Drain: every wave waits vmcnt(0) entering the barrier -> all h quanta of
    // this block are at the coherence point before the flag is published.
    __syncthreads();

    // ---------- publish progress ----------
    if (tid == 0)
      __hip_atomic_store(&pflag[l * TPL + tile], (unsigned)(t + 1), __ATOMIC_RELAXED,
                         __HIP_MEMORY_SCOPE_AGENT);

    // ---------- out stores (fire-and-forget, off critical path) ----------
    if (l == NL - 1) {
      f32x4 o = {v[0], v[1], v[2], v[3]};
      __builtin_nontemporal_store(
          o, reinterpret_cast<f32x4*>(out + ((size_t)rb * LL + t) * HH + c0 + c4));
    }
    if (t == LL - 1) {
      f32x4 o = {v[0], v[1], v[2], v[3]};
      __builtin_nontemporal_store(
          o, reinterpret_cast<f32x4*>(out + (size_t)BB * LL * HH +
                                      ((size_t)l * BB + rb) * HH + c0 + c4));
    }
  }
}

extern "C" void kernel_launch(void* const* d_in, const int* in_sizes, int n_in,
                              void* d_out, int out_size, void* d_ws, size_t ws_size,
                              hipStream_t stream) {
  const float* x  = (const float*)d_in[0];
  const float* h0 = (const float*)d_in[1];
  const float* WI = (const float*)d_in[2];
  const float* BI = (const float*)d_in[3];
  const float* WH = (const float*)d_in[4];
  const float* BH = (const float*)d_in[5];
  float* out = (float*)d_out;

  const size_t hbytes = (size_t)NL * RS * BB * HH * sizeof(_Float16);  // 16.8 MB
  _Float16* hbuf = (_Float16*)d_ws;
  unsigned* pflag = (unsigned*)((char*)d_ws + hbytes);

  // 0xFF: every f16 LSB=1 -> invalid for generation-0 (parity 0) consumers.
  hipMemsetAsync(hbuf, 0xFF, hbytes, stream);
  hipMemsetAsync(pflag, 0, (size_t)NL * TPL * sizeof(unsigned), stream);
  rnn_persist<<<256, 256, 0, stream>>>(x, h0, WI, BI, WH, BH, out, hbuf, pflag);
}